// Round 5
// baseline (15.207 us; speedup 1.0000x reference)
//
#include <hip/hip_runtime.h>

// PointGraphic2d: 4096x4096 f32 canvas, zero everywhere except a ~40px disk
// around p = key_points[0]*4096. Pure HBM-write problem (64 MiB stores/call;
// MALL does not absorb streaming store misses - verified round 4).
//
// Round 5: fill-kernel-like shape. 1024 blocks x 256 threads, 4 rows/block,
// 16 float4 stores/thread. All blocks co-resident (4/CU) -> single dispatch
// round, no block-turnover gaps; each wave streams 16 independent 16B stores.

typedef float floatx4 __attribute__((ext_vector_type(4)));

__global__ __launch_bounds__(256) void point_graphic2d_kernel(
    const float* __restrict__ key_points, float* __restrict__ out) {
  constexpr int H = 4096;
  constexpr int W = 4096;
  constexpr int W4 = W / 4;        // 1024 float4 per row
  constexpr int ROWS_PER_BLOCK = 4;
  constexpr float WIDTH = 20.0f;
  constexpr float EPS = 0.001f;
  constexpr float INV_MAXD = 1.0f / 5792.61880957152f;  // 1/(4096*sqrt(2))

  const int y0 = blockIdx.x * ROWS_PER_BLOCK;
  const int t = threadIdx.x;

  const float py = key_points[0] * (float)H;
  const float px = key_points[1] * (float)W;

  const floatx4 z = {0.0f, 0.0f, 0.0f, 0.0f};

#pragma unroll
  for (int r = 0; r < ROWS_PER_BLOCK; ++r) {
    const int y = y0 + r;
    const float dy = (float)y - py;
    floatx4* __restrict__ row =
        reinterpret_cast<floatx4*>(out) + (size_t)y * W4;

    if (fabsf(dy) >= WIDTH) {
      // Fast path: row-uniform streaming zero-fill (4 stores, no per-store ALU).
#pragma unroll
      for (int k = 0; k < 4; ++k) {
        row[t + k * 256] = z;
      }
    } else {
      // Disk row: compute per pixel (~41 of 4096 rows).
      const float dy2 = dy * dy;
#pragma unroll
      for (int k = 0; k < 4; ++k) {
        const int c = t + k * 256;      // float4 chunk index in row
        const float fx0 = (float)(c << 2);
        floatx4 v = {0.0f, 0.0f, 0.0f, 0.0f};
        if (fx0 + 3.0f > px - WIDTH && fx0 < px + WIDTH) {
#pragma unroll
          for (int j = 0; j < 4; ++j) {
            const float dx = fx0 + (float)j - px;
            const float dist = sqrtf(dy2 + dx * dx);
            if (dist < WIDTH) {
              v[j] = 1.0f - (dist * INV_MAXD + EPS);
            }
          }
        }
        row[c] = v;
      }
    }
  }
}

extern "C" void kernel_launch(void* const* d_in, const int* in_sizes, int n_in,
                              void* d_out, int out_size, void* d_ws, size_t ws_size,
                              hipStream_t stream) {
  const float* key_points = (const float*)d_in[0];
  float* out = (float*)d_out;

  dim3 grid(1024);   // 4 rows per block; all blocks co-resident (4/CU)
  dim3 block(256);   // 16x 16B stores per thread
  hipLaunchKernelGGL(point_graphic2d_kernel, grid, block, 0, stream,
                     key_points, out);
}